// Round 9
// baseline (376.795 us; speedup 1.0000x reference)
//
#include <hip/hip_runtime.h>
#include <hip/hip_bf16.h>
#include <float.h>

#define T_LEN 2048
#define DM    1024
#define NB    128
#define NEGC  (-1e9f)

typedef __attribute__((ext_vector_type(8))) short short8;
typedef __attribute__((ext_vector_type(4))) float floatx4;
typedef _Float16 h2 __attribute__((ext_vector_type(2)));

// ---------------- helpers ----------------
__device__ __forceinline__ float wred_max(float v) {
#pragma unroll
  for (int o = 32; o > 0; o >>= 1) v = fmaxf(v, __shfl_xor(v, o, 64));
  return v;
}
__device__ __forceinline__ float wred_sum(float v) {
#pragma unroll
  for (int o = 32; o > 0; o >>= 1) v += __shfl_xor(v, o, 64);
  return v;
}
__device__ __forceinline__ unsigned short f32_to_bf16(float f) {
  unsigned int b = __float_as_uint(f);
  return (unsigned short)((b + 0x7fffu + ((b >> 16) & 1u)) >> 16);
}
__device__ __forceinline__ float bf16_to_f32(unsigned short u) {
  return __uint_as_float(((unsigned int)u) << 16);
}
__device__ __forceinline__ unsigned int pack_h2(float a, float b) {
  h2 r; r[0] = (_Float16)a; r[1] = (_Float16)b;
  return __builtin_bit_cast(unsigned int, r);
}
__device__ __forceinline__ float fdot2u(unsigned int a, unsigned int b, float c) {
#if __has_builtin(__builtin_amdgcn_fdot2)
  return __builtin_amdgcn_fdot2(__builtin_bit_cast(h2, a), __builtin_bit_cast(h2, b), c, false);
#else
  const h2 av = __builtin_bit_cast(h2, a), bv = __builtin_bit_cast(h2, b);
  return c + (float)av[0] * (float)bv[0] + (float)av[1] * (float)bv[1];
#endif
}
__device__ __forceinline__ void lds_async16(unsigned short* l, const unsigned short* g) {
  __builtin_amdgcn_global_load_lds(
      (const __attribute__((address_space(1))) unsigned int*)g,
      (__attribute__((address_space(3))) unsigned int*)l, 16, 0, 0);
}

// ===== 128x128-tile bf16 MFMA GEMM, chunk-major swizzled LDS, fused epilogue =====
// 4 waves 2x2, BK=32, 16 MFMA/wave/barrier (m97 density). LDS layout:
// row r, chunk kgrp at shorts (r>>6)*2048 + ((r>>4)&3)*512 + kgrp*128 + (r&15)*8
// -> fragment reads hit banks mrow*4 mod 32 (2-way aliasing = free; r8: 0 conflicts).
// Epilogue scatters q|k|v directly to consumer layouts (reorg kernel deleted).
__global__ __launch_bounds__(256) void qkv_gemm(
    const unsigned short* __restrict__ Axx, const unsigned short* __restrict__ Bqkv,
    const unsigned short* __restrict__ Wvt,
    float* __restrict__ qh, unsigned short* __restrict__ qhf,
    float* __restrict__ khf32, unsigned short* __restrict__ khfT,
    unsigned short* __restrict__ vhf) {
  __shared__ __align__(16) unsigned short As[128 * 32];
  __shared__ __align__(16) unsigned short Bs[128 * 32];
  const int ct = blockIdx.x;
  const int row0 = blockIdx.y * 128;
  const unsigned short* Bt;
  int K, bcol0;
  if (ct < 16) { Bt = Bqkv; K = 3072; bcol0 = ct * 128; }
  else         { Bt = Wvt;  K = 1024; bcol0 = (ct - 16) * 128; }

  const int tid = threadIdx.x;
  const int w = tid >> 6, lane = tid & 63;
  const int wr = w >> 1, wc = w & 1;
  const int mrow = lane & 15, kgrp = lane >> 4;
  const int sr = (w << 4) + mrow;  // staged row 0..63 (this inst), +64 for second

  floatx4 zero = {0.f, 0.f, 0.f, 0.f};
  floatx4 acc[4][4];
#pragma unroll
  for (int i = 0; i < 4; i++)
#pragma unroll
    for (int j = 0; j < 4; j++) acc[i][j] = zero;

  for (int k0 = 0; k0 < K; k0 += 32) {
    lds_async16(&As[w * 512],        Axx + (size_t)(row0 + sr) * 3072 + k0 + kgrp * 8);
    lds_async16(&As[2048 + w * 512], Axx + (size_t)(row0 + 64 + sr) * 3072 + k0 + kgrp * 8);
    lds_async16(&Bs[w * 512],        Bt + (size_t)(bcol0 + sr) * K + k0 + kgrp * 8);
    lds_async16(&Bs[2048 + w * 512], Bt + (size_t)(bcol0 + 64 + sr) * K + k0 + kgrp * 8);
    __syncthreads();
    short8 af[4], bf[4];
#pragma unroll
    for (int mi = 0; mi < 4; mi++)
      af[mi] = *(const short8*)&As[wr * 2048 + mi * 512 + kgrp * 128 + mrow * 8];
#pragma unroll
    for (int ni = 0; ni < 4; ni++)
      bf[ni] = *(const short8*)&Bs[wc * 2048 + ni * 512 + kgrp * 128 + mrow * 8];
#pragma unroll
    for (int mi = 0; mi < 4; mi++)
#pragma unroll
      for (int ni = 0; ni < 4; ni++)
        acc[mi][ni] = __builtin_amdgcn_mfma_f32_16x16x32_bf16(af[mi], bf[ni], acc[mi][ni], 0, 0, 0);
    __syncthreads();
  }

  // fused epilogue: scatter to consumer layouts
#pragma unroll
  for (int mi = 0; mi < 4; mi++) {
    const int t = row0 + wr * 64 + mi * 16 + kgrp * 4;  // rows t..t+3
#pragma unroll
    for (int ni = 0; ni < 4; ni++) {
      const int c = ct * 128 + wc * 64 + ni * 16 + mrow;
      if (ct < 8) {
        // ---- q: qh f32 (T,1024) + qhf f16 packed pairs
#pragma unroll
        for (int r = 0; r < 4; r++) {
          const float v = acc[mi][ni][r];
          qh[(size_t)(t + r) * 1024 + c] = v;
          const float other = __shfl_xor(v, 1, 64);
          if ((lane & 1) == 0)
            *(unsigned int*)&qhf[(size_t)(t + r) * 1024 + c] = pack_h2(v, other);
        }
      } else if (ct < 16) {
        // ---- k: khf32 f32 (H,T,64) + khfT f16 (H,8,T,8)
        const int ck = c - 1024, hh = ck >> 6, d = ck & 63;
#pragma unroll
        for (int r = 0; r < 4; r++) {
          const float v = acc[mi][ni][r];
          khf32[((size_t)hh * 2048 + t + r) * 64 + d] = v;
          const float other = __shfl_xor(v, 1, 64);
          if ((lane & 1) == 0)
            *(unsigned int*)&khfT[((size_t)(hh * 8 + (d >> 3)) * 2048 + t + r) * 8 + (d & 7)] =
                pack_h2(v, other);
        }
      } else {
        // ---- v: vhf f16 (H,T,64)
        const int cv = c - 2048, hh = cv >> 6, d = cv & 63;
#pragma unroll
        for (int r = 0; r < 4; r++) {
          const float v = acc[mi][ni][r];
          const float other = __shfl_xor(v, 1, 64);
          if ((lane & 1) == 0)
            *(unsigned int*)&vhf[((size_t)hh * 2048 + t + r) * 64 + d] = pack_h2(v, other);
        }
      }
    }
  }
}

// generic 64x128 GEMM (output projection; conflict-free swizzle)
__device__ __forceinline__ void gemm64_core(
    const unsigned short* __restrict__ A, const unsigned short* __restrict__ Bt,
    float* __restrict__ C, int K, int lda, int row0, int bcol0, int ccol0, int ldc,
    unsigned short* As, unsigned short* Bs) {
  const int tid = threadIdx.x;
  const int w = tid >> 6, lane = tid & 63;
  const int wr = w >> 1, wc = w & 1;
  const int mrow = lane & 15, kgrp = lane >> 4;
  const int sr = (w << 4) + mrow;

  floatx4 zero = {0.f, 0.f, 0.f, 0.f};
  floatx4 acc[2][4];
#pragma unroll
  for (int i = 0; i < 2; i++)
#pragma unroll
    for (int j = 0; j < 4; j++) acc[i][j] = zero;

  for (int k0 = 0; k0 < K; k0 += 32) {
    lds_async16(&As[w * 512], A + (size_t)(row0 + sr) * lda + k0 + kgrp * 8);
    lds_async16(&Bs[w * 512], Bt + (size_t)(bcol0 + sr) * K + k0 + kgrp * 8);
    lds_async16(&Bs[2048 + w * 512], Bt + (size_t)(bcol0 + 64 + sr) * K + k0 + kgrp * 8);
    __syncthreads();
    short8 af[2], bf[4];
#pragma unroll
    for (int mi = 0; mi < 2; mi++)
      af[mi] = *(const short8*)&As[(wr * 2 + mi) * 512 + kgrp * 128 + mrow * 8];
#pragma unroll
    for (int ni = 0; ni < 4; ni++)
      bf[ni] = *(const short8*)&Bs[wc * 2048 + ni * 512 + kgrp * 128 + mrow * 8];
#pragma unroll
    for (int mi = 0; mi < 2; mi++)
#pragma unroll
      for (int ni = 0; ni < 4; ni++)
        acc[mi][ni] = __builtin_amdgcn_mfma_f32_16x16x32_bf16(af[mi], bf[ni], acc[mi][ni], 0, 0, 0);
    __syncthreads();
  }
#pragma unroll
  for (int mi = 0; mi < 2; mi++)
#pragma unroll
    for (int ni = 0; ni < 4; ni++) {
      float* Cp = C + (size_t)(row0 + wr * 32 + mi * 16 + kgrp * 4) * ldc
                    + ccol0 + wc * 64 + ni * 16 + mrow;
      Cp[0] = acc[mi][ni][0];
      Cp[(size_t)ldc] = acc[mi][ni][1];
      Cp[(size_t)2 * ldc] = acc[mi][ni][2];
      Cp[(size_t)3 * ldc] = acc[mi][ni][3];
    }
}

__global__ __launch_bounds__(256) void gemm_bt64(const unsigned short* __restrict__ A,
                                                 const unsigned short* __restrict__ Bt,
                                                 float* __restrict__ C,
                                                 int K, int lda, int ldc) {
  __shared__ __align__(16) unsigned short As[64 * 32];
  __shared__ __align__(16) unsigned short Bs[128 * 32];
  gemm64_core(A, Bt, C, K, lda, blockIdx.y * 64,
              blockIdx.x * 128, blockIdx.x * 128, ldc, As, Bs);
}

// ---------------- cast x -> A'' = [x_hi | x_lo | x_hi] ----------------
__global__ __launch_bounds__(256) void cast_x_k(const float* __restrict__ x,
                                                unsigned short* __restrict__ Axx) {
  const int gid = blockIdx.x * 256 + threadIdx.x;
  float4 xv = ((const float4*)x)[gid];
  const int m = gid >> 8;
  const int c = (gid & 255) * 4;
  float vv[4] = {xv.x, xv.y, xv.z, xv.w};
  unsigned short h[4], l[4];
#pragma unroll
  for (int j = 0; j < 4; j++) {
    h[j] = f32_to_bf16(vv[j]);
    l[j] = f32_to_bf16(vv[j] - bf16_to_f32(h[j]));
  }
  ushort4 hv = make_ushort4(h[0], h[1], h[2], h[3]);
  ushort4 lv = make_ushort4(l[0], l[1], l[2], l[3]);
  *(ushort4*)&Axx[(size_t)m * 3072 + c] = hv;
  *(ushort4*)&Axx[(size_t)m * 3072 + 1024 + c] = lv;
  *(ushort4*)&Axx[(size_t)m * 3072 + 2048 + c] = hv;
}

// ---- transpose-cast Wq/Wk into Bqkv hi/hi/lo rows (K=3072) ----
__global__ void cast_wt3(const float* __restrict__ Wq, const float* __restrict__ Wk,
                         unsigned short* __restrict__ Bt) {
  __shared__ float tile[32][33];
  const float* W = (blockIdx.z == 0) ? Wq : Wk;
  const int n0 = blockIdx.z * 1024;
  const int kt0 = blockIdx.y * 32, nt0 = blockIdx.x * 32;
  const int tx = threadIdx.x, ty = threadIdx.y;
#pragma unroll
  for (int i = 0; i < 32; i += 8)
    tile[ty + i][tx] = W[(size_t)(kt0 + ty + i) * 1024 + nt0 + tx];
  __syncthreads();
#pragma unroll
  for (int i = 0; i < 32; i += 8) {
    const int n = nt0 + ty + i, kk = kt0 + tx;
    const float f = tile[tx][ty + i];
    const unsigned short hb = f32_to_bf16(f);
    const unsigned short lb = f32_to_bf16(f - bf16_to_f32(hb));
    const size_t base = (size_t)(n0 + n) * 3072;
    Bt[base + kk] = hb;
    Bt[base + 1024 + kk] = hb;
    Bt[base + 2048 + kk] = lb;
  }
}

// ---- transpose-cast 1024x1024 W -> Bt (1024n x 1024k) bf16 ----
__global__ void cast_wt1(const float* __restrict__ W, unsigned short* __restrict__ Bt) {
  __shared__ float tile[32][33];
  const int kt0 = blockIdx.y * 32, nt0 = blockIdx.x * 32;
  const int tx = threadIdx.x, ty = threadIdx.y;
#pragma unroll
  for (int i = 0; i < 32; i += 8)
    tile[ty + i][tx] = W[(size_t)(kt0 + ty + i) * 1024 + nt0 + tx];
  __syncthreads();
#pragma unroll
  for (int i = 0; i < 32; i += 8) {
    const int n = nt0 + ty + i, kk = kt0 + tx;
    Bt[(size_t)n * 1024 + kk] = f32_to_bf16(tile[tx][ty + i]);
  }
}

// ---- transpose-cast Wck/Wcv (1024x64) -> (64,1024) hi/lo bf16 ----
__global__ void cast_wct(const float* __restrict__ Wck, const float* __restrict__ Wcv,
                         unsigned short* __restrict__ KT_hi, unsigned short* __restrict__ KT_lo,
                         unsigned short* __restrict__ VT_hi, unsigned short* __restrict__ VT_lo) {
  __shared__ float tile[32][33];
  const float* W = blockIdx.z ? Wcv : Wck;
  unsigned short* Bh = blockIdx.z ? VT_hi : KT_hi;
  unsigned short* Bl = blockIdx.z ? VT_lo : KT_lo;
  const int kt0 = blockIdx.y * 32, nt0 = blockIdx.x * 32;
  const int tx = threadIdx.x, ty = threadIdx.y;
#pragma unroll
  for (int i = 0; i < 32; i += 8)
    tile[ty + i][tx] = W[(size_t)(kt0 + ty + i) * 64 + nt0 + tx];
  __syncthreads();
#pragma unroll
  for (int i = 0; i < 32; i += 8) {
    const int n = nt0 + ty + i, kk = kt0 + tx;
    const float f = tile[tx][ty + i];
    const unsigned short hb = f32_to_bf16(f);
    Bh[(size_t)n * 1024 + kk] = hb;
    Bl[(size_t)n * 1024 + kk] = f32_to_bf16(f - bf16_to_f32(hb));
  }
}

// ---------------- compress via MFMA: k from khf32 (fp32), v from vhf (f16) ----
__global__ __launch_bounds__(256) void compress_mfma(
    const float* __restrict__ khf32, const unsigned short* __restrict__ vhf,
    const unsigned short* __restrict__ KT_hi, const unsigned short* __restrict__ KT_lo,
    const unsigned short* __restrict__ VT_hi, const unsigned short* __restrict__ VT_lo,
    unsigned short* __restrict__ kc_hi, unsigned short* __restrict__ kc_lo,
    unsigned short* __restrict__ vcT) {
  const int isv = blockIdx.y;
  const unsigned short* Bh = isv ? VT_hi : KT_hi;
  const unsigned short* Bl = isv ? VT_lo : KT_lo;
  const int tid = threadIdx.x, w = tid >> 6, lane = tid & 63;
  const int mrow = lane & 15, kgrp = lane >> 4;
  const int m0 = blockIdx.x * 64 + w * 16;
  const int m = m0 + mrow;               // h*128 + nb
  const int hh = m >> 7, nb = m & 127;
  const size_t abase = ((size_t)hh * 2048 + nb * 16) * 64;  // token-block K-vector

  floatx4 zero = {0.f, 0.f, 0.f, 0.f};
  floatx4 acc[4] = {zero, zero, zero, zero};

  for (int k0 = 0; k0 < 1024; k0 += 32) {
    const int c = k0 + kgrp * 8;
    float qq[8];
    short8 a_hi, a_lo;
    if (!isv) {
      const float* ap = &khf32[abase + c];
      float4 q0 = *(const float4*)ap;
      float4 q1 = *(const float4*)(ap + 4);
      qq[0] = q0.x; qq[1] = q0.y; qq[2] = q0.z; qq[3] = q0.w;
      qq[4] = q1.x; qq[5] = q1.y; qq[6] = q1.z; qq[7] = q1.w;
#pragma unroll
      for (int j = 0; j < 8; j++) {
        unsigned short hb = f32_to_bf16(qq[j]);
        a_hi[j] = (short)hb;
        a_lo[j] = (short)f32_to_bf16(qq[j] - bf16_to_f32(hb));
      }
    } else {
      const uint4 vv = *(const uint4*)&vhf[abase + c];
      const unsigned int uu[4] = {vv.x, vv.y, vv.z, vv.w};
#pragma unroll
      for (int j2 = 0; j2 < 4; j2++) {
        const h2 p = __builtin_bit_cast(h2, uu[j2]);
        qq[2 * j2] = (float)p[0];
        qq[2 * j2 + 1] = (float)p[1];
      }
#pragma unroll
      for (int j = 0; j < 8; j++) a_hi[j] = (short)f32_to_bf16(qq[j]);
    }
#pragma unroll
    for (int ni = 0; ni < 4; ni++) {
      const size_t boff = (size_t)(ni * 16 + mrow) * 1024 + k0 + kgrp * 8;
      short8 b_hi = *(const short8*)&Bh[boff];
      short8 b_lo = *(const short8*)&Bl[boff];
      acc[ni] = __builtin_amdgcn_mfma_f32_16x16x32_bf16(a_hi, b_hi, acc[ni], 0, 0, 0);
      if (!isv)
        acc[ni] = __builtin_amdgcn_mfma_f32_16x16x32_bf16(a_lo, b_hi, acc[ni], 0, 0, 0);
      acc[ni] = __builtin_amdgcn_mfma_f32_16x16x32_bf16(a_hi, b_lo, acc[ni], 0, 0, 0);
    }
  }
#pragma unroll
  for (int ni = 0; ni < 4; ni++)
#pragma unroll
    for (int r = 0; r < 4; r++) {
      const int mo = m0 + kgrp * 4 + r;
      const int d = ni * 16 + mrow;
      const float val = acc[ni][r];
      if (!isv) {
        const unsigned short hb = f32_to_bf16(val);
        kc_hi[(size_t)mo * 64 + d] = hb;
        kc_lo[(size_t)mo * 64 + d] = f32_to_bf16(val - bf16_to_f32(hb));
      } else {
        vcT[(size_t)(mo >> 7) * 8192 + (size_t)d * 128 + (mo & 127)] = f32_to_bf16(val);
      }
    }
}

// ---------------- gates (reads qh) ----------------
__global__ __launch_bounds__(256) void gates_k(const float* __restrict__ qh,
                                               const float* __restrict__ Wg,
                                               const float* __restrict__ bg,
                                               float* __restrict__ gates) {
  const int w = threadIdx.x >> 6, lane = threadIdx.x & 63;
  const int t = blockIdx.x * 4 + w;
  float m = 0.f;
#pragma unroll
  for (int h = 0; h < 16; h++) m += qh[(size_t)t * 1024 + h * 64 + lane];
  m *= (1.f / 16.f);
  float g0 = wred_sum(m * Wg[lane * 3 + 0]);
  float g1 = wred_sum(m * Wg[lane * 3 + 1]);
  float g2 = wred_sum(m * Wg[lane * 3 + 2]);
  if (lane == 0) {
    g0 += bg[0]; g1 += bg[1]; g2 += bg[2];
    float mx = fmaxf(g0, fmaxf(g1, g2));
    float e0 = __expf(g0 - mx), e1 = __expf(g1 - mx), e2 = __expf(g2 - mx);
    float inv = 1.f / (e0 + e1 + e2);
    gates[t * 3 + 0] = e0 * inv;
    gates[t * 3 + 1] = e1 * inv;
    gates[t * 3 + 2] = e2 * inv;
  }
}

// ---------------- cscore: MFMA scores + softmax + top-4 -> P (bf16), sel ----
__global__ __launch_bounds__(256) void cscore_k(
    const float* __restrict__ qh, const unsigned short* __restrict__ kc_hi,
    const unsigned short* __restrict__ kc_lo, unsigned short* __restrict__ P,
    int4* __restrict__ sel) {
  __shared__ float S_s[16][132];
  const int h = blockIdx.x >> 7, t0 = (blockIdx.x & 127) * 16;
  const int tid = threadIdx.x, w = tid >> 6, lane = tid & 63;
  const int mrow = lane & 15, kgrp = lane >> 4;

  short8 a_hi[2], a_lo[2];
#pragma unroll
  for (int ks = 0; ks < 2; ks++) {
    const float* qp = &qh[(size_t)(t0 + mrow) * 1024 + h * 64 + ks * 32 + kgrp * 8];
    float4 q0 = *(const float4*)qp;
    float4 q1 = *(const float4*)(qp + 4);
    float qq[8] = {q0.x, q0.y, q0.z, q0.w, q1.x, q1.y, q1.z, q1.w};
#pragma unroll
    for (int j = 0; j < 8; j++) {
      unsigned short hb = f32_to_bf16(qq[j]);
      a_hi[ks][j] = (short)hb;
      a_lo[ks][j] = (short)f32_to_bf16(qq[j] - bf16_to_f32(hb));
    }
  }
  floatx4 zero = {0.f, 0.f, 0.f, 0.f};
  floatx4 acc[2] = {zero, zero};
#pragma unroll
  for (int ni = 0; ni < 2; ni++) {
    const int nb = w * 32 + ni * 16 + mrow;
#pragma unroll
    for (int ks = 0; ks < 2; ks++) {
      const size_t off = ((size_t)h * 128 + nb) * 64 + ks * 32 + kgrp * 8;
      short8 b_hi = *(const short8*)&kc_hi[off];
      short8 b_lo = *(const short8*)&kc_lo[off];
      acc[ni] = __builtin_amdgcn_mfma_f32_16x16x32_bf16(a_hi[ks], b_hi, acc[ni], 0, 0, 0);
      acc[ni] = __builtin_amdgcn_mfma_f32_16x16x32_bf16(a_lo[ks], b_hi, acc[ni], 0, 0, 0);
      acc[ni] = __builtin_amdgcn_mfma_f32_16x16x32_bf16(a_hi[ks], b_lo, acc[ni], 0, 0, 0);
    }
  }
#pragma unroll
  for (int ni = 0; ni < 2; ni++) {
    const int n = w * 32 + ni * 16 + mrow;
#pragma unroll
    for (int r = 0; r < 4; r++) {
      const int row = kgrp * 4 + r;
      const int count = (t0 + row) >> 4;
      S_s[row][n] = (n < count) ? acc[ni][r] * 0.125f : NEGC;
    }
  }
  __syncthreads();

  for (int qq = 0; qq < 4; qq++) {
    const int row = w * 4 + qq, t = t0 + row, count = t >> 4;
    const float2 sv = *(const float2*)&S_s[row][2 * lane];
    const float s0 = sv.x, s1 = sv.y;
    const float M = wred_max(fmaxf(s0, s1));
    const float e0 = __expf(s0 - M), e1 = __expf(s1 - M);
    const float inv = 1.f / wred_sum(e0 + e1);
    ushort2 pv;
    pv.x = (count == 0) ? (unsigned short)0 : f32_to_bf16(e0 * inv);
    pv.y = (count == 0) ? (unsigned short)0 : f32_to_bf16(e1 * inv);
    *(ushort2*)&P[(((size_t)h << 11) + t) * 128 + 2 * lane] = pv;

    float c0 = s0, c1 = s1;
    int sel0 = 0, sel1 = 0, sel2 = 0, sel3 = 0;
#pragma unroll
    for (int j = 0; j < 4; j++) {
      float bv; int bi;
      if (c0 >= c1) { bv = c0; bi = 2 * lane; } else { bv = c1; bi = 2 * lane + 1; }
#pragma unroll
      for (int o = 32; o > 0; o >>= 1) {
        const float ov = __shfl_xor(bv, o, 64);
        const int oi = __shfl_xor(bi, o, 64);
        if (ov > bv || (ov == bv && oi < bi)) { bv = ov; bi = oi; }
      }
      if (j == 0) sel0 = bi; else if (j == 1) sel1 = bi;
      else if (j == 2) sel2 = bi; else sel3 = bi;
      if (bi == 2 * lane) c0 = -FLT_MAX;
      if (bi == 2 * lane + 1) c1 = -FLT_MAX;
    }
    if (lane == 0) sel[((size_t)h << 11) + t] = make_int4(sel0, sel1, sel2, sel3);
  }
}

// ---------------- out_c = P @ vc : MFMA, fragment-direct, no LDS ----------------
__global__ __launch_bounds__(256) void outc_k(const unsigned short* __restrict__ P,
                                              const unsigned short* __restrict__ vcT,
                                              float* __restrict__ oc) {
  const int h = blockIdx.x >> 4, t0 = (blockIdx.x & 15) * 128;
  const int tid = threadIdx.x, w = tid >> 6, lane = tid & 63;
  const int mrow = lane & 15, kgrp = lane >> 4;
  floatx4 zero = {0.f, 0.f, 0.f, 0.f};
  floatx4 acc[2][4];
#pragma unroll
  for (int mi = 0; mi < 2; mi++)
#pragma unroll
    for (int ni = 0; ni < 4; ni++) acc[mi][ni] = zero;

#pragma unroll
  for (int ks = 0; ks < 4; ks++) {
    short8 a[2];
#pragma unroll
    for (int mi = 0; mi < 2; mi++) {
      const int t = t0 + w * 32 + mi * 16 + mrow;
      a[mi] = *(const short8*)&P[(((size_t)h << 11) + t) * 128 + ks * 32 + kgrp * 8];
    }
#pragma unroll
    for (int ni = 0; ni < 4; ni++) {
      const int d = ni * 16 + mrow;
      short8 b = *(const short8*)&vcT[((size_t)h * 64 + d) * 128 + ks * 32 + kgrp * 8];
      acc[0][ni] = __builtin_amdgcn_mfma_f32_16x16x32_bf16(a[0], b, acc[0][ni], 0, 0, 0);
      acc[1][ni] = __builtin_amdgcn_mfma_f32_16x16x32_bf16(a[1], b, acc[1][ni], 0, 0, 0);
    }
  }
#pragma unroll
  for (int mi = 0; mi < 2; mi++)
#pragma unroll
    for (int ni = 0; ni < 4; ni++)
#pragma unroll
      for (int r = 0; r < 4; r++)
        oc[(size_t)(t0 + w * 32 + mi * 16 + kgrp * 4 + r) * 1024 + h * 64 + ni * 16 + mrow] =
            acc[mi][ni][r];
}

// ---------------- selected + window branches + gated combine ----------------
__global__ __launch_bounds__(256) void nsa_swl(
    const unsigned short* __restrict__ qhf, const unsigned short* __restrict__ khfT,
    const unsigned short* __restrict__ vhf, const int4* __restrict__ sel,
    const float* __restrict__ oc, const float* __restrict__ gates,
    unsigned short* __restrict__ outf) {
  __shared__ float ps[4][64];
  const int bid = blockIdx.x;
  const int h = ((bid & 7) << 1) | ((bid >> 3) & 1);
  const int w = threadIdx.x >> 6, lane = threadIdx.x & 63;
  const int t = (bid >> 4) * 4 + w;

  const unsigned short* kT = khfT + (size_t)h * 131072;
  const unsigned short* vhh = vhf + (size_t)h * 131072;

  uint4 qr[8];
  {
    const uint4* qp = (const uint4*)(qhf + (size_t)t * 1024 + h * 64);
#pragma unroll
    for (int j = 0; j < 8; j++) qr[j] = qp[j];
  }
  const int4 s4 = sel[((size_t)h << 11) + t];

  const int g16 = lane >> 4;
  const int blk = (g16 == 0) ? s4.x : (g16 == 1) ? s4.y : (g16 == 2) ? s4.z : s4.w;
  const int tok = blk * 16 + (lane & 15);
  {
    float a0 = 0.f, a1 = 0.f, a2 = 0.f, a3 = 0.f;
#pragma unroll
    for (int dc = 0; dc < 8; dc++) {
      const uint4 kk = *(const uint4*)(kT + ((size_t)dc * 2048 + tok) * 8);
      a0 = fdot2u(kk.x, qr[dc].x, a0);
      a1 = fdot2u(kk.y, qr[dc].y, a1);
      a2 = fdot2u(kk.z, qr[dc].z, a2);
      a3 = fdot2u(kk.w, qr[dc].w, a3);
    }
    const float sv_ = (tok <= t) ? ((a0 + a1) + (a2 + a3)) * 0.125f : NEGC;
    const float Ms = wred_max(sv_);
    const float es = __expf(sv_ - Ms);
    ps[w][lane] = es * (1.f / wred_sum(es));
  }

  const int dd = lane & 31, s = lane >> 5;
  const float4* ps4 = (const float4*)ps[w];

  float osx = 0.f, osy = 0.f;
#pragma unroll
  for (int jc = 0; jc < 8; jc++) {
    const float4 p4 = ps4[s * 8 + jc];
    const float pa[4] = {p4.x, p4.y, p4.z, p4.w};
#pragma unroll
    for (int u = 0; u < 4; u++) {
      const int idx = s * 32 + jc * 4 + u;
      const int jb = idx >> 4;
      const int b2 = (jb == 0) ? s4.x : (jb == 1) ? s4.y : (jb == 2) ? s4.z : s4.w;
      const int tok2 = b2 * 16 + (idx & 15);
      const unsigned int vv = *(const unsigned int*)(vhh + (size_t)tok2 * 64 + 2 * dd);
      const h2 v2 = __builtin_bit_cast(h2, vv);
      osx += pa[u] * (float)v2[0];
      osy += pa[u] * (float)v2[1];
    }
  }
  osx += __shfl_xor(osx, 32, 64);
  osy += __shfl_xor(osy, 32, 64);

  {
    const int tw = t - 32 + lane;
    const int twc = min(max(tw, 0), T_LEN - 1);
    float a0 = 0.f, a1 = 0.f, a2 = 0.f, a3 = 0.f;
#pragma unroll
    for (int dc = 0; dc < 8; dc++) {
      const uint4 kk = *(const uint4*)(kT + ((size_t)dc * 2048 + twc) * 8);
      a0 = fdot2u(kk.x, qr[dc].x, a0);
      a1 = fdot2u(kk.y, qr[dc].y, a1);
      a2 = fdot2u(kk.z, qr[dc].z, a2);
      a3 = fdot2u(kk.w, qr[dc].w, a3);
    }
    const float swv = (tw >= 0 && lane <= 32) ? ((a0 + a1) + (a2 + a3)) * 0.125f : NEGC;
    const float Mw = wred_max(swv);
    const float ew = __expf(swv - Mw);
    ps[w][lane] = ew * (1.f / wred_sum(ew));
  }

  float olx = 0.f, oly = 0.f;
#pragma unroll
  for (int j = 0; j < 17; j++) {
    const int idx = s * 17 + j;
    const int idc = min(idx, 32);
    const float p = (idx <= 32) ? ps[w][idc] : 0.f;
    const int tk = min(max(t - 32 + idx, 0), T_LEN - 1);
    const unsigned int vv = *(const unsigned int*)(vhh + (size_t)tk * 64 + 2 * dd);
    const h2 v2 = __builtin_bit_cast(h2, vv);
    olx += p * (float)v2[0];
    oly += p * (float)v2[1];
  }
  olx += __shfl_xor(olx, 32, 64);
  oly += __shfl_xor(oly, 32, 64);

  if (lane < 32) {
    const float2 ocv = *(const float2*)&oc[(size_t)t * 1024 + h * 64 + 2 * dd];
    const float g0 = gates[t * 3 + 0], g1 = gates[t * 3 + 1], g2 = gates[t * 3 + 2];
    const float r0 = g0 * ocv.x + g1 * osx + g2 * olx;
    const float r1 = g0 * ocv.y + g1 * osy + g2 * oly;
    const unsigned int pk = (unsigned int)f32_to_bf16(r0) | ((unsigned int)f32_to_bf16(r1) << 16);
    *(unsigned int*)&outf[(size_t)t * DM + h * 64 + 2 * dd] = pk;
  }
}

// ---------------- launch ----------------
extern "C" void kernel_launch(void* const* d_in, const int* in_sizes, int n_in,
                              void* d_out, int out_size, void* d_ws, size_t ws_size,
                              hipStream_t stream) {
  const float* x   = (const float*)d_in[0];
  const float* Wq  = (const float*)d_in[1];
  const float* Wk  = (const float*)d_in[2];
  const float* Wv  = (const float*)d_in[3];
  const float* Wo  = (const float*)d_in[4];
  const float* Wck = (const float*)d_in[5];
  const float* Wcv = (const float*)d_in[6];
  const float* Wg  = (const float*)d_in[7];
  const float* bg  = (const float*)d_in[8];
  float* out = (float*)d_out;

  float* ws = (float*)d_ws;
  // [0,24 MB): Axx(12) + Bqkv(12) until qkv_gemm; then P(8)/oc(8)/outf(4)
  unsigned short* Axx  = (unsigned short*)ws;
  unsigned short* Bqkv = (unsigned short*)(ws + 3145728);
  unsigned short* P    = (unsigned short*)ws;               // [0,8)
  float*          oc   = ws + 2097152;                      // [8,16)
  unsigned short* outf = (unsigned short*)(ws + 4194304);   // [16,20)
  // [24,52 MB): qkv_gemm fused outputs
  float*          qh    = ws + 6291456;                     // [24,32)
  unsigned short* qhf   = (unsigned short*)(ws + 8388608);  // [32,36)
  float*          khf32 = ws + 9437184;                     // [36,44)
  unsigned short* khfT  = (unsigned short*)(ws + 11534336); // [44,48)
  unsigned short* vhf   = (unsigned short*)(ws + 12582912); // [48,52)
  // [52 MB ...): smalls
  unsigned short* Wot   = (unsigned short*)(ws + 13631488); // [52,54)
  unsigned short* kc_hi = (unsigned short*)(ws + 14155776);
  unsigned short* kc_lo = (unsigned short*)(ws + 14221312);
  unsigned short* vcT   = (unsigned short*)(ws + 14286848);
  int4*           sel   = (int4*)(ws + 14352384);
  unsigned short* WckT_hi = (unsigned short*)(ws + 14483456);
  unsigned short* WckT_lo = (unsigned short*)(ws + 14516224);
  unsigned short* WcvT_hi = (unsigned short*)(ws + 14548992);
  unsigned short* WcvT_lo = (unsigned short*)(ws + 14581760);
  float*          gates   = ws + 14614528;
  // Wvt scratch in d_out (consumed by qkv_gemm before final GEMM writes out)
  unsigned short* Wvt = (unsigned short*)d_out;             // 2 MB

  // 1. operand preparation
  cast_x_k<<<2048, 256, 0, stream>>>(x, Axx);
  cast_wt3<<<dim3(32, 32, 2), dim3(32, 8), 0, stream>>>(Wq, Wk, Bqkv);
  cast_wt1<<<dim3(32, 32), dim3(32, 8), 0, stream>>>(Wv, Wvt);
  cast_wt1<<<dim3(32, 32), dim3(32, 8), 0, stream>>>(Wo, Wot);
  cast_wct<<<dim3(2, 32, 2), dim3(32, 8), 0, stream>>>(Wck, Wcv, WckT_hi, WckT_lo, WcvT_hi, WcvT_lo);

  // 2. merged q|k|v GEMM, 128x128 swizzled tiles, fused reorg epilogue
  qkv_gemm<<<dim3(24, 16), 256, 0, stream>>>(Axx, Bqkv, Wvt, qh, qhf, khf32, khfT, vhf);

  // 3. gates + compression + compressed branch
  gates_k<<<512, 256, 0, stream>>>(qh, Wg, bg, gates);
  compress_mfma<<<dim3(32, 2), 256, 0, stream>>>(khf32, vhf, WckT_hi, WckT_lo, WcvT_hi, WcvT_lo,
                                                 kc_hi, kc_lo, vcT);
  cscore_k<<<2048, 256, 0, stream>>>(qh, kc_hi, kc_lo, P, sel);
  outc_k<<<256, 256, 0, stream>>>(P, vcT, oc);

  // 4. selected + window + gated combine
  nsa_swl<<<8192, 256, 0, stream>>>(qhf, khfT, vhf, sel, oc, gates, outf);

  // 5. output projection
  gemm_bt64<<<dim3(8, 32), 256, 0, stream>>>(outf, Wot, out, 1024, 1024, 1024);
}

// Round 12
// 362.703 us; speedup vs baseline: 1.0389x; 1.0389x over previous
//
#include <hip/hip_runtime.h>
#include <hip/hip_bf16.h>
#include <float.h>

#define T_LEN 2048
#define DM    1024
#define NB    128
#define NEGC  (-1e9f)

typedef __attribute__((ext_vector_type(8))) short short8;
typedef __attribute__((ext_vector_type(4))) float floatx4;
typedef _Float16 h2 __attribute__((ext_vector_type(2)));

// ---------------- helpers ----------------
__device__ __forceinline__ float wred_max(float v) {
#pragma unroll
  for (int o = 32; o > 0; o >>= 1) v = fmaxf(v, __shfl_xor(v, o, 64));
  return v;
}
__device__ __forceinline__ float wred_sum(float v) {
#pragma unroll
  for (int o = 32; o > 0; o >>= 1) v += __shfl_xor(v, o, 64);
  return v;
}
__device__ __forceinline__ unsigned short f32_to_bf16(float f) {
  unsigned int b = __float_as_uint(f);
  return (unsigned short)((b + 0x7fffu + ((b >> 16) & 1u)) >> 16);
}
__device__ __forceinline__ float bf16_to_f32(unsigned short u) {
  return __uint_as_float(((unsigned int)u) << 16);
}
__device__ __forceinline__ unsigned int pack_h2(float a, float b) {
  h2 r; r[0] = (_Float16)a; r[1] = (_Float16)b;
  return __builtin_bit_cast(unsigned int, r);
}
__device__ __forceinline__ float fdot2u(unsigned int a, unsigned int b, float c) {
#if __has_builtin(__builtin_amdgcn_fdot2)
  return __builtin_amdgcn_fdot2(__builtin_bit_cast(h2, a), __builtin_bit_cast(h2, b), c, false);
#else
  const h2 av = __builtin_bit_cast(h2, a), bv = __builtin_bit_cast(h2, b);
  return c + (float)av[0] * (float)bv[0] + (float)av[1] * (float)bv[1];
#endif
}
__device__ __forceinline__ void lds_async16(unsigned short* l, const unsigned short* g) {
  __builtin_amdgcn_global_load_lds(
      (const __attribute__((address_space(1))) unsigned int*)g,
      (__attribute__((address_space(3))) unsigned int*)l, 16, 0, 0);
}

// ===== 128x128-tile bf16 MFMA GEMM: chunk-major swizzled LDS, single buffer =====
// r9-verified core (passed correctness). 4 waves 2x2, BK=32, 16 MFMA/wave/barrier.
__device__ __forceinline__ void gemm128(
    const unsigned short* __restrict__ A, const unsigned short* __restrict__ Bt,
    float* __restrict__ C, int K, int lda, int row0, int bcol0, int ccol0, int ldc,
    unsigned short* As, unsigned short* Bs) {
  const int tid = threadIdx.x;
  const int w = tid >> 6, lane = tid & 63;
  const int wr = w >> 1, wc = w & 1;
  const int mrow = lane & 15, kgrp = lane >> 4;
  const int sr = (w << 4) + mrow;

  floatx4 zero = {0.f, 0.f, 0.f, 0.f};
  floatx4 acc[4][4];
#pragma unroll
  for (int i = 0; i < 4; i++)
#pragma unroll
    for (int j = 0; j < 4; j++) acc[i][j] = zero;

  for (int k0 = 0; k0 < K; k0 += 32) {
    lds_async16(&As[w * 512],        A + (size_t)(row0 + sr) * lda + k0 + kgrp * 8);
    lds_async16(&As[2048 + w * 512], A + (size_t)(row0 + 64 + sr) * lda + k0 + kgrp * 8);
    lds_async16(&Bs[w * 512],        Bt + (size_t)(bcol0 + sr) * K + k0 + kgrp * 8);
    lds_async16(&Bs[2048 + w * 512], Bt + (size_t)(bcol0 + 64 + sr) * K + k0 + kgrp * 8);
    __syncthreads();
    short8 af[4], bf[4];
#pragma unroll
    for (int mi = 0; mi < 4; mi++)
      af[mi] = *(const short8*)&As[wr * 2048 + mi * 512 + kgrp * 128 + mrow * 8];
#pragma unroll
    for (int ni = 0; ni < 4; ni++)
      bf[ni] = *(const short8*)&Bs[wc * 2048 + ni * 512 + kgrp * 128 + mrow * 8];
#pragma unroll
    for (int mi = 0; mi < 4; mi++)
#pragma unroll
      for (int ni = 0; ni < 4; ni++)
        acc[mi][ni] = __builtin_amdgcn_mfma_f32_16x16x32_bf16(af[mi], bf[ni], acc[mi][ni], 0, 0, 0);
    __syncthreads();
  }
#pragma unroll
  for (int mi = 0; mi < 4; mi++)
#pragma unroll
    for (int ni = 0; ni < 4; ni++) {
      float* Cp = C + (size_t)(row0 + wr * 64 + mi * 16 + kgrp * 4) * ldc
                    + ccol0 + wc * 64 + ni * 16 + mrow;
      Cp[0] = acc[mi][ni][0];
      Cp[(size_t)ldc] = acc[mi][ni][1];
      Cp[(size_t)2 * ldc] = acc[mi][ni][2];
      Cp[(size_t)3 * ldc] = acc[mi][ni][3];
    }
}

// merged q|k|v GEMM: grid (24,16). ct<16: Bqkv (K=3072, bf16x3 split qk);
// ct>=16: Wvt (K=1024, plain). A = Axx for both (v uses the x_hi columns).
__global__ __launch_bounds__(256) void qkv_gemm(const unsigned short* __restrict__ Axx,
                                                const unsigned short* __restrict__ Bqkv,
                                                const unsigned short* __restrict__ Wvt,
                                                float* __restrict__ C) {
  __shared__ __align__(16) unsigned short As[128 * 32];
  __shared__ __align__(16) unsigned short Bs[128 * 32];
  const int ct = blockIdx.x;
  const unsigned short* Bt;
  int K, bcol0;
  if (ct < 16) { Bt = Bqkv; K = 3072; bcol0 = ct * 128; }
  else         { Bt = Wvt;  K = 1024; bcol0 = (ct - 16) * 128; }
  gemm128(Axx, Bt, C, K, 3072, blockIdx.y * 128, bcol0, ct * 128, 3072, As, Bs);
}

// 64x128-tile GEMM for the output projection (r8-verified)
__device__ __forceinline__ void gemm64_core(
    const unsigned short* __restrict__ A, const unsigned short* __restrict__ Bt,
    float* __restrict__ C, int K, int lda, int row0, int bcol0, int ccol0, int ldc,
    unsigned short* As, unsigned short* Bs) {
  const int tid = threadIdx.x;
  const int w = tid >> 6, lane = tid & 63;
  const int wr = w >> 1, wc = w & 1;
  const int mrow = lane & 15, kgrp = lane >> 4;
  const int sr = (w << 4) + mrow;

  floatx4 zero = {0.f, 0.f, 0.f, 0.f};
  floatx4 acc[2][4];
#pragma unroll
  for (int i = 0; i < 2; i++)
#pragma unroll
    for (int j = 0; j < 4; j++) acc[i][j] = zero;

  for (int k0 = 0; k0 < K; k0 += 32) {
    lds_async16(&As[w * 512], A + (size_t)(row0 + sr) * lda + k0 + kgrp * 8);
    lds_async16(&Bs[w * 512], Bt + (size_t)(bcol0 + sr) * K + k0 + kgrp * 8);
    lds_async16(&Bs[2048 + w * 512], Bt + (size_t)(bcol0 + 64 + sr) * K + k0 + kgrp * 8);
    __syncthreads();
    short8 af[2], bf[4];
#pragma unroll
    for (int mi = 0; mi < 2; mi++)
      af[mi] = *(const short8*)&As[(wr * 2 + mi) * 512 + kgrp * 128 + mrow * 8];
#pragma unroll
    for (int ni = 0; ni < 4; ni++)
      bf[ni] = *(const short8*)&Bs[wc * 2048 + ni * 512 + kgrp * 128 + mrow * 8];
#pragma unroll
    for (int mi = 0; mi < 2; mi++)
#pragma unroll
      for (int ni = 0; ni < 4; ni++)
        acc[mi][ni] = __builtin_amdgcn_mfma_f32_16x16x32_bf16(af[mi], bf[ni], acc[mi][ni], 0, 0, 0);
    __syncthreads();
  }
#pragma unroll
  for (int mi = 0; mi < 2; mi++)
#pragma unroll
    for (int ni = 0; ni < 4; ni++) {
      float* Cp = C + (size_t)(row0 + wr * 32 + mi * 16 + kgrp * 4) * ldc
                    + ccol0 + wc * 64 + ni * 16 + mrow;
      Cp[0] = acc[mi][ni][0];
      Cp[(size_t)ldc] = acc[mi][ni][1];
      Cp[(size_t)2 * ldc] = acc[mi][ni][2];
      Cp[(size_t)3 * ldc] = acc[mi][ni][3];
    }
}

__global__ __launch_bounds__(256) void gemm_bt64(const unsigned short* __restrict__ A,
                                                 const unsigned short* __restrict__ Bt,
                                                 float* __restrict__ C,
                                                 int K, int lda, int ldc) {
  __shared__ __align__(16) unsigned short As[64 * 32];
  __shared__ __align__(16) unsigned short Bs[128 * 32];
  gemm64_core(A, Bt, C, K, lda, blockIdx.y * 64,
              blockIdx.x * 128, blockIdx.x * 128, ldc, As, Bs);
}

// ---------------- cast x -> A'' = [x_hi | x_lo | x_hi] ----------------
__global__ __launch_bounds__(256) void cast_x_k(const float* __restrict__ x,
                                                unsigned short* __restrict__ Axx) {
  const int gid = blockIdx.x * 256 + threadIdx.x;
  float4 xv = ((const float4*)x)[gid];
  const int m = gid >> 8;
  const int c = (gid & 255) * 4;
  float vv[4] = {xv.x, xv.y, xv.z, xv.w};
  unsigned short h[4], l[4];
#pragma unroll
  for (int j = 0; j < 4; j++) {
    h[j] = f32_to_bf16(vv[j]);
    l[j] = f32_to_bf16(vv[j] - bf16_to_f32(h[j]));
  }
  ushort4 hv = make_ushort4(h[0], h[1], h[2], h[3]);
  ushort4 lv = make_ushort4(l[0], l[1], l[2], l[3]);
  *(ushort4*)&Axx[(size_t)m * 3072 + c] = hv;
  *(ushort4*)&Axx[(size_t)m * 3072 + 1024 + c] = lv;
  *(ushort4*)&Axx[(size_t)m * 3072 + 2048 + c] = hv;
}

// ---- merged weight casts: z=0/1 Wq/Wk->Bqkv(3-split); z=2 Wv->Wvt; z=3 Wo->Wot;
//      z=4/5 Wck/Wcv -> (64,1024) hi/lo bf16.
// NOTE (r10/r11 bug): ALL destinations must live OUTSIDE Axx/Bqkv's live ranges
// since this runs BEFORE qkv_gemm. Wot/WckT/WcvT now placed past 48 MB.
__global__ void cast_w_all(const float* __restrict__ Wq, const float* __restrict__ Wk,
                           const float* __restrict__ Wv, const float* __restrict__ Wo,
                           const float* __restrict__ Wck, const float* __restrict__ Wcv,
                           unsigned short* __restrict__ Bqkv,
                           unsigned short* __restrict__ Wvt, unsigned short* __restrict__ Wot,
                           unsigned short* __restrict__ KT_hi, unsigned short* __restrict__ KT_lo,
                           unsigned short* __restrict__ VT_hi, unsigned short* __restrict__ VT_lo) {
  __shared__ float tile[32][33];
  const int z = blockIdx.z;
  const int kt0 = blockIdx.y * 32, nt0 = blockIdx.x * 32;
  const int tx = threadIdx.x, ty = threadIdx.y;

  if (z < 2) {
    const float* W = z ? Wk : Wq;
    const int n0 = z * 1024;
#pragma unroll
    for (int i = 0; i < 32; i += 8)
      tile[ty + i][tx] = W[(size_t)(kt0 + ty + i) * 1024 + nt0 + tx];
    __syncthreads();
#pragma unroll
    for (int i = 0; i < 32; i += 8) {
      const int n = nt0 + ty + i, kk = kt0 + tx;
      const float f = tile[tx][ty + i];
      const unsigned short hb = f32_to_bf16(f);
      const unsigned short lb = f32_to_bf16(f - bf16_to_f32(hb));
      const size_t base = (size_t)(n0 + n) * 3072;
      Bqkv[base + kk] = hb;
      Bqkv[base + 1024 + kk] = hb;
      Bqkv[base + 2048 + kk] = lb;
    }
  } else if (z < 4) {
    const float* W = (z == 2) ? Wv : Wo;
    unsigned short* dst = (z == 2) ? Wvt : Wot;
#pragma unroll
    for (int i = 0; i < 32; i += 8)
      tile[ty + i][tx] = W[(size_t)(kt0 + ty + i) * 1024 + nt0 + tx];
    __syncthreads();
#pragma unroll
    for (int i = 0; i < 32; i += 8) {
      const int n = nt0 + ty + i, kk = kt0 + tx;
      dst[(size_t)n * 1024 + kk] = f32_to_bf16(tile[tx][ty + i]);
    }
  } else {
    if (blockIdx.x >= 2) return;  // Wck/Wcv have only 64 output rows
    const float* W = (z == 4) ? Wck : Wcv;
    unsigned short* Bh = (z == 4) ? KT_hi : VT_hi;
    unsigned short* Bl = (z == 4) ? KT_lo : VT_lo;
#pragma unroll
    for (int i = 0; i < 32; i += 8)
      tile[ty + i][tx] = W[(size_t)(kt0 + ty + i) * 64 + nt0 + tx];
    __syncthreads();
#pragma unroll
    for (int i = 0; i < 32; i += 8) {
      const int n = nt0 + ty + i, kk = kt0 + tx;
      const float f = tile[tx][ty + i];
      const unsigned short hb = f32_to_bf16(f);
      Bh[(size_t)n * 1024 + kk] = hb;
      Bl[(size_t)n * 1024 + kk] = f32_to_bf16(f - bf16_to_f32(hb));
    }
  }
}

// ---------------- reorg: C(t,3072) -> qh f32, qhf f16 (T,1024),
//                  khfT f16 (H,8,T,8), vhf f16 (H,T,64) ----------------
__global__ __launch_bounds__(256) void reorg_qkv(const float* __restrict__ C,
                                                 float* __restrict__ qh,
                                                 unsigned short* __restrict__ qhf,
                                                 unsigned short* __restrict__ khfT,
                                                 unsigned short* __restrict__ vhf) {
  const int gid = blockIdx.x * 256 + threadIdx.x;
  const int t = gid / 768;
  const int c = (gid - t * 768) * 4;
  float4 val = *(const float4*)&C[(size_t)t * 3072 + c];
  const unsigned int p0 = pack_h2(val.x, val.y);
  const unsigned int p1 = pack_h2(val.z, val.w);
  if (c < 1024) {
    *(float4*)&qh[(size_t)t * 1024 + c] = val;
    *(uint2*)&qhf[(size_t)t * 1024 + c] = make_uint2(p0, p1);
  } else if (c < 2048) {
    const int h = (c >> 6) & 15, d = c & 63;
    const int dc = d >> 3, j = d & 7;
    *(uint2*)&khfT[((size_t)(h * 8 + dc) * 2048 + t) * 8 + j] = make_uint2(p0, p1);
  } else {
    const int h = (c >> 6) & 15, d = c & 63;
    *(uint2*)&vhf[((size_t)h * 2048 + t) * 64 + d] = make_uint2(p0, p1);
  }
}

// ---------------- compress via MFMA (reads k/v straight from C) ----------------
__global__ __launch_bounds__(256) void compress_mfma(
    const float* __restrict__ C,
    const unsigned short* __restrict__ KT_hi, const unsigned short* __restrict__ KT_lo,
    const unsigned short* __restrict__ VT_hi, const unsigned short* __restrict__ VT_lo,
    unsigned short* __restrict__ kc_hi, unsigned short* __restrict__ kc_lo,
    unsigned short* __restrict__ vcT) {
  const int isv = blockIdx.y;
  const unsigned short* Bh = isv ? VT_hi : KT_hi;
  const unsigned short* Bl = isv ? VT_lo : KT_lo;
  const int tid = threadIdx.x, w = tid >> 6, lane = tid & 63;
  const int mrow = lane & 15, kgrp = lane >> 4;
  const int m0 = blockIdx.x * 64 + w * 16;
  const int m = m0 + mrow;
  const int hh = m >> 7, nb = m & 127;
  const int cbase = 1024 + isv * 1024 + hh * 64;

  floatx4 zero = {0.f, 0.f, 0.f, 0.f};
  floatx4 acc[4] = {zero, zero, zero, zero};

  for (int k0 = 0; k0 < 1024; k0 += 32) {
    const int c = k0 + kgrp * 8;
    const float* ap = &C[(size_t)(nb * 16 + (c >> 6)) * 3072 + cbase + (c & 63)];
    float4 q0 = *(const float4*)ap;
    float4 q1 = *(const float4*)(ap + 4);
    float qq[8] = {q0.x, q0.y, q0.z, q0.w, q1.x, q1.y, q1.z, q1.w};
    short8 a_hi, a_lo;
#pragma unroll
    for (int j = 0; j < 8; j++) {
      unsigned short hb = f32_to_bf16(qq[j]);
      a_hi[j] = (short)hb;
      a_lo[j] = (short)f32_to_bf16(qq[j] - bf16_to_f32(hb));
    }
#pragma unroll
    for (int ni = 0; ni < 4; ni++) {
      const size_t boff = (size_t)(ni * 16 + mrow) * 1024 + k0 + kgrp * 8;
      short8 b_hi = *(const short8*)&Bh[boff];
      short8 b_lo = *(const short8*)&Bl[boff];
      acc[ni] = __builtin_amdgcn_mfma_f32_16x16x32_bf16(a_hi, b_hi, acc[ni], 0, 0, 0);
      acc[ni] = __builtin_amdgcn_mfma_f32_16x16x32_bf16(a_lo, b_hi, acc[ni], 0, 0, 0);
      acc[ni] = __builtin_amdgcn_mfma_f32_16x16x32_bf16(a_hi, b_lo, acc[ni], 0, 0, 0);
    }
  }
#pragma unroll
  for (int ni = 0; ni < 4; ni++)
#pragma unroll
    for (int r = 0; r < 4; r++) {
      const int mo = m0 + kgrp * 4 + r;
      const int d = ni * 16 + mrow;
      const float val = acc[ni][r];
      if (!isv) {
        const unsigned short hb = f32_to_bf16(val);
        kc_hi[(size_t)mo * 64 + d] = hb;
        kc_lo[(size_t)mo * 64 + d] = f32_to_bf16(val - bf16_to_f32(hb));
      } else {
        vcT[(size_t)(mo >> 7) * 8192 + (size_t)d * 128 + (mo & 127)] = f32_to_bf16(val);
      }
    }
}

// ---------------- gates (reads C q-columns) ----------------
__global__ __launch_bounds__(256) void gates_k(const float* __restrict__ C,
                                               const float* __restrict__ Wg,
                                               const float* __restrict__ bg,
                                               float* __restrict__ gates) {
  const int w = threadIdx.x >> 6, lane = threadIdx.x & 63;
  const int t = blockIdx.x * 4 + w;
  float m = 0.f;
#pragma unroll
  for (int h = 0; h < 16; h++) m += C[(size_t)t * 3072 + h * 64 + lane];
  m *= (1.f / 16.f);
  float g0 = wred_sum(m * Wg[lane * 3 + 0]);
  float g1 = wred_sum(m * Wg[lane * 3 + 1]);
  float g2 = wred_sum(m * Wg[lane * 3 + 2]);
  if (lane == 0) {
    g0 += bg[0]; g1 += bg[1]; g2 += bg[2];
    float mx = fmaxf(g0, fmaxf(g1, g2));
    float e0 = __expf(g0 - mx), e1 = __expf(g1 - mx), e2 = __expf(g2 - mx);
    float inv = 1.f / (e0 + e1 + e2);
    gates[t * 3 + 0] = e0 * inv;
    gates[t * 3 + 1] = e1 * inv;
    gates[t * 3 + 2] = e2 * inv;
  }
}

// ---------------- cscore: MFMA scores + softmax + top-4 -> P (bf16), sel ----
__global__ __launch_bounds__(256) void cscore_k(
    const float* __restrict__ qh, const unsigned short* __restrict__ kc_hi,
    const unsigned short* __restrict__ kc_lo, unsigned short* __restrict__ P,
    int4* __restrict__ sel) {
  __shared__ float S_s[16][132];
  const int h = blockIdx.x >> 7, t0 = (blockIdx.x & 127) * 16;
  const int tid = threadIdx.x, w = tid >> 6, lane = tid & 63;
  const int mrow = lane & 15, kgrp = lane >> 4;

  short8 a_hi[2], a_lo[2];
#pragma unroll
  for (int ks = 0; ks < 2; ks++) {
    const float* qp = &qh[(size_t)(t0 + mrow) * 1024 + h * 64 + ks * 32 + kgrp * 8];
    float4 q0 = *(const float4*)qp;
    float4 q1 = *(const float4*)(qp + 4);
    float qq[8] = {q0.x, q0.y, q0.z, q0.w, q1.x, q1.y, q1.z, q1.w};
#pragma unroll
    for (int j = 0; j < 8; j++) {
      unsigned short hb = f32_to_bf16(qq[j]);
      a_hi[ks][j] = (short)hb;
      a_lo[ks][j] = (short)f32_to_bf16(qq[j] - bf16_to_f32(hb));
    }
  }
  floatx4 zero = {0.f, 0.f, 0.f, 0.f};
  floatx4 acc[2] = {zero, zero};
#pragma unroll
  for (int ni = 0; ni < 2; ni++) {
    const int nb = w * 32 + ni * 16 + mrow;
#pragma unroll
    for (int ks = 0; ks < 2; ks++) {
      const size_t off = ((size_t)h * 128 + nb) * 64 + ks * 32 + kgrp * 8;
      short8 b_hi = *(const short8*)&kc_hi[off];
      short8 b_lo = *(const short8*)&kc_lo[off];
      acc[ni] = __builtin_amdgcn_mfma_f32_16x16x32_bf16(a_hi[ks], b_hi, acc[ni], 0, 0, 0);
      acc[ni] = __builtin_amdgcn_mfma_f32_16x16x32_bf16(a_lo[ks], b_hi, acc[ni], 0, 0, 0);
      acc[ni] = __builtin_amdgcn_mfma_f32_16x16x32_bf16(a_hi[ks], b_lo, acc[ni], 0, 0, 0);
    }
  }
#pragma unroll
  for (int ni = 0; ni < 2; ni++) {
    const int n = w * 32 + ni * 16 + mrow;
#pragma unroll
    for (int r = 0; r < 4; r++) {
      const int row = kgrp * 4 + r;
      const int count = (t0 + row) >> 4;
      S_s[row][n] = (n < count) ? acc[ni][r] * 0.125f : NEGC;
    }
  }
  __syncthreads();

  for (int qq = 0; qq < 4; qq++) {
    const int row = w * 4 + qq, t = t0 + row, count = t >> 4;
    const float2 sv = *(const float2*)&S_s[row][2 * lane];
    const float s0 = sv.x, s1 = sv.y;
    const float M = wred_max(fmaxf(s0, s1));
    const float e0 = __expf(s0 - M), e1 = __expf(s1 - M);
    const float inv = 1.f / wred_sum(e0 + e1);
    ushort2 pv;
    pv.x = (count == 0) ? (unsigned short)0 : f32_to_bf16(e0 * inv);
    pv.y = (count == 0) ? (unsigned short)0 : f32_to_bf16(e1 * inv);
    *(ushort2*)&P[(((size_t)h << 11) + t) * 128 + 2 * lane] = pv;

    float c0 = s0, c1 = s1;
    int sel0 = 0, sel1 = 0, sel2 = 0, sel3 = 0;
#pragma unroll
    for (int j = 0; j < 4; j++) {
      float bv; int bi;
      if (c0 >= c1) { bv = c0; bi = 2 * lane; } else { bv = c1; bi = 2 * lane + 1; }
#pragma unroll
      for (int o = 32; o > 0; o >>= 1) {
        const float ov = __shfl_xor(bv, o, 64);
        const int oi = __shfl_xor(bi, o, 64);
        if (ov > bv || (ov == bv && oi < bi)) { bv = ov; bi = oi; }
      }
      if (j == 0) sel0 = bi; else if (j == 1) sel1 = bi;
      else if (j == 2) sel2 = bi; else sel3 = bi;
      if (bi == 2 * lane) c0 = -FLT_MAX;
      if (bi == 2 * lane + 1) c1 = -FLT_MAX;
    }
    if (lane == 0) sel[((size_t)h << 11) + t] = make_int4(sel0, sel1, sel2, sel3);
  }
}

// ---------------- out_c = P @ vc : MFMA, fragment-direct, no LDS ----------------
__global__ __launch_bounds__(256) void outc_k(const unsigned short* __restrict__ P,
                                              const unsigned short* __restrict__ vcT,
                                              float* __restrict__ oc) {
  const int h = blockIdx.x >> 4, t0 = (blockIdx.x & 15) * 128;
  const int tid = threadIdx.x, w = tid >> 6, lane = tid & 63;
  const int mrow = lane & 15, kgrp = lane >> 4;
  floatx4 zero = {0.f, 0.f, 0.f, 0.f};
  floatx4 acc[2][4];
#pragma unroll
  for (int mi = 0; mi < 2; mi++)
#pragma unroll
    for (int ni = 0; ni < 4; ni++) acc[mi][ni] = zero;

#pragma unroll
  for (int ks = 0; ks < 4; ks++) {
    short8 a[2];
#pragma unroll
    for (int mi = 0; mi < 2; mi++) {
      const int t = t0 + w * 32 + mi * 16 + mrow;
      a[mi] = *(const short8*)&P[(((size_t)h << 11) + t) * 128 + ks * 32 + kgrp * 8];
    }
#pragma unroll
    for (int ni = 0; ni < 4; ni++) {
      const int d = ni * 16 + mrow;
      short8 b = *(const short8*)&vcT[((size_t)h * 64 + d) * 128 + ks * 32 + kgrp * 8];
      acc[0][ni] = __builtin_amdgcn_mfma_f32_16x16x32_bf16(a[0], b, acc[0][ni], 0, 0, 0);
      acc[1][ni] = __builtin_amdgcn_mfma_f32_16x16x32_bf16(a[1], b, acc[1][ni], 0, 0, 0);
    }
  }
#pragma unroll
  for (int mi = 0; mi < 2; mi++)
#pragma unroll
    for (int ni = 0; ni < 4; ni++)
#pragma unroll
      for (int r = 0; r < 4; r++)
        oc[(size_t)(t0 + w * 32 + mi * 16 + kgrp * 4 + r) * 1024 + h * 64 + ni * 16 + mrow] =
            acc[mi][ni][r];
}

// ---------------- selected + window branches + gated combine ----------------
__global__ __launch_bounds__(256) void nsa_swl(
    const unsigned short* __restrict__ qhf, const unsigned short* __restrict__ khfT,
    const unsigned short* __restrict__ vhf, const int4* __restrict__ sel,
    const float* __restrict__ oc, const float* __restrict__ gates,
    unsigned short* __restrict__ outf) {
  __shared__ float ps[4][64];
  const int bid = blockIdx.x;
  const int h = ((bid & 7) << 1) | ((bid >> 3) & 1);
  const int w = threadIdx.x >> 6, lane = threadIdx.x & 63;
  const int t = (bid >> 4) * 4 + w;

  const unsigned short* kT = khfT + (size_t)h * 131072;
  const unsigned short* vhh = vhf + (size_t)h * 131072;

  uint4 qr[8];
  {
    const uint4* qp = (const uint4*)(qhf + (size_t)t * 1024 + h * 64);
#pragma unroll
    for (int j = 0; j < 8; j++) qr[j] = qp[j];
  }
  const int4 s4 = sel[((size_t)h << 11) + t];

  const int g16 = lane >> 4;
  const int blk = (g16 == 0) ? s4.x : (g16 == 1) ? s4.y : (g16 == 2) ? s4.z : s4.w;
  const int tok = blk * 16 + (lane & 15);
  {
    float a0 = 0.f, a1 = 0.f, a2 = 0.f, a3 = 0.f;
#pragma unroll
    for (int dc = 0; dc < 8; dc++) {
      const uint4 kk = *(const uint4*)(kT + ((size_t)dc * 2048 + tok) * 8);
      a0 = fdot2u(kk.x, qr[dc].x, a0);
      a1 = fdot2u(kk.y, qr[dc].y, a1);
      a2 = fdot2u(kk.z, qr[dc].z, a2);
      a3 = fdot2u(kk.w, qr[dc].w, a3);
    }
    const float sv_ = (tok <= t) ? ((a0 + a1) + (a2 + a3)) * 0.125f : NEGC;
    const float Ms = wred_max(sv_);
    const float es = __expf(sv_ - Ms);
    ps[w][lane] = es * (1.f / wred_sum(es));
  }

  const int dd = lane & 31, s = lane >> 5;
  const float4* ps4 = (const float4*)ps[w];

  float osx = 0.f, osy = 0.f;
#pragma unroll
  for (int jc = 0; jc < 8; jc++) {
    const float4 p4 = ps4[s * 8 + jc];
    const float pa[4] = {p4.x, p4.y, p4.z, p4.w};
#pragma unroll
    for (int u = 0; u < 4; u++) {
      const int idx = s * 32 + jc * 4 + u;
      const int jb = idx >> 4;
      const int b2 = (jb == 0) ? s4.x : (jb == 1) ? s4.y : (jb == 2) ? s4.z : s4.w;
      const int tok2 = b2 * 16 + (idx & 15);
      const unsigned int vv = *(const unsigned int*)(vhh + (size_t)tok2 * 64 + 2 * dd);
      const h2 v2 = __builtin_bit_cast(h2, vv);
      osx += pa[u] * (float)v2[0];
      osy += pa[u] * (float)v2[1];
    }
  }
  osx += __shfl_xor(osx, 32, 64);
  osy += __shfl_xor(osy, 32, 64);

  {
    const int tw = t - 32 + lane;
    const int twc = min(max(tw, 0), T_LEN - 1);
    float a0 = 0.f, a1 = 0.f, a2 = 0.f, a3 = 0.f;
#pragma unroll
    for (int dc = 0; dc < 8; dc++) {
      const uint4 kk = *(const uint4*)(kT + ((size_t)dc * 2048 + twc) * 8);
      a0 = fdot2u(kk.x, qr[dc].x, a0);
      a1 = fdot2u(kk.y, qr[dc].y, a1);
      a2 = fdot2u(kk.z, qr[dc].z, a2);
      a3 = fdot2u(kk.w, qr[dc].w, a3);
    }
    const float swv = (tw >= 0 && lane <= 32) ? ((a0 + a1) + (a2 + a3)) * 0.125f : NEGC;
    const float Mw = wred_max(swv);
    const float ew = __expf(swv - Mw);
    ps[w][lane] = ew * (1.f / wred_sum(ew));
  }

  float olx = 0.f, oly = 0.f;
#pragma unroll
  for (int j = 0; j < 17; j++) {
    const int idx = s * 17 + j;
    const int idc = min(idx, 32);
    const float p = (idx <= 32) ? ps[w][idc] : 0.f;
    const int tk = min(max(t - 32 + idx, 0), T_LEN - 1);
    const unsigned int vv = *(const unsigned int*)(vhh + (size_t)tk * 64 + 2 * dd);
    const h2 v2 = __builtin_bit_cast(h2, vv);
    olx += p * (float)v2[0];
    oly += p * (float)v2[1];
  }
  olx += __shfl_xor(olx, 32, 64);
  oly += __shfl_xor(oly, 32, 64);

  if (lane < 32) {
    const float2 ocv = *(const float2*)&oc[(size_t)t * 1024 + h * 64 + 2 * dd];
    const float g0 = gates[t * 3 + 0], g1 = gates[t * 3 + 1], g2 = gates[t * 3 + 2];
    const float r0 = g0 * ocv.x + g1 * osx + g2 * olx;
    const float r1 = g0 * ocv.y + g1 * osy + g2 * oly;
    const unsigned int pk = (unsigned int)f32_to_bf16(r0) | ((unsigned int)f32_to_bf16(r1) << 16);
    *(unsigned int*)&outf[(size_t)t * DM + h * 64 + 2 * dd] = pk;
  }
}

// ---------------- launch ----------------
extern "C" void kernel_launch(void* const* d_in, const int* in_sizes, int n_in,
                              void* d_out, int out_size, void* d_ws, size_t ws_size,
                              hipStream_t stream) {
  const float* x   = (const float*)d_in[0];
  const float* Wq  = (const float*)d_in[1];
  const float* Wk  = (const float*)d_in[2];
  const float* Wv  = (const float*)d_in[3];
  const float* Wo  = (const float*)d_in[4];
  const float* Wck = (const float*)d_in[5];
  const float* Wcv = (const float*)d_in[6];
  const float* Wg  = (const float*)d_in[7];
  const float* bg  = (const float*)d_in[8];
  float* out = (float*)d_out;

  float* ws = (float*)d_ws;
  // ---- memory map (byte ranges). Weight-cast outputs MUST NOT overlap
  //      Axx [24,36) or Bqkv [36,48), which are live until qkv_gemm. ----
  // [0,24 MB): C until compress_mfma; then P/oc/outf
  float*          C    = ws;
  unsigned short* P    = (unsigned short*)ws;               // [0,8)
  float*          oc   = ws + 2097152;                      // [8,16)
  unsigned short* outf = (unsigned short*)(ws + 4194304);   // [16,20)
  // [24,36 MB): Axx until qkv_gemm; then qh [24,32)
  unsigned short* Axx  = (unsigned short*)(ws + 6291456);
  float*          qh   = ws + 6291456;
  // [36,48 MB): Bqkv until qkv_gemm; then qhf/khfT/vhf f16
  unsigned short* Bqkv = (unsigned short*)(ws + 9437184);
  unsigned short* qhf  = (unsigned short*)(ws + 9437184);   // [36,40)
  unsigned short* khfT = (unsigned short*)(ws + 10485760);  // [40,44)
  unsigned short* vhf  = (unsigned short*)(ws + 11534336);  // [44,48)
  // [48 MB ...): cast outputs + smalls (SAFE: past all overlays)
  unsigned short* Wot   = (unsigned short*)(ws + 12582912); // [48,50)
  unsigned short* kc_hi = (unsigned short*)(ws + 13107200); // [50.00,50.25)
  unsigned short* kc_lo = (unsigned short*)(ws + 13172736);
  unsigned short* vcT   = (unsigned short*)(ws + 13238272);
  int4*           sel   = (int4*)(ws + 13303808);           // 512 KB
  unsigned short* WckT_hi = (unsigned short*)(ws + 13434880);
  unsigned short* WckT_lo = (unsigned short*)(ws + 13467648);
  unsigned short* WcvT_hi = (unsigned short*)(ws + 13500416);
  unsigned short* WcvT_lo = (unsigned short*)(ws + 13533184);
  float*          gates   = ws + 13565952;                  // ends ~54.3 MB
  // Wvt scratch in d_out (consumed by qkv_gemm before final GEMM writes out)
  unsigned short* Wvt = (unsigned short*)d_out;             // 2 MB

  // 1. operand preparation (2 launches)
  cast_x_k<<<2048, 256, 0, stream>>>(x, Axx);
  cast_w_all<<<dim3(32, 32, 6), dim3(32, 8), 0, stream>>>(
      Wq, Wk, Wv, Wo, Wck, Wcv, Bqkv, Wvt, Wot, WckT_hi, WckT_lo, WcvT_hi, WcvT_lo);

  // 2. merged q|k|v GEMM: 128x128 swizzled tiles, single-buffered (r9-verified)
  qkv_gemm<<<dim3(24, 16), 256, 0, stream>>>(Axx, Bqkv, Wvt, C);

  // 3. reorg + gates (C stays alive for compress)
  reorg_qkv<<<6144, 256, 0, stream>>>(C, qh, qhf, khfT, vhf);
  gates_k<<<512, 256, 0, stream>>>(C, Wg, bg, gates);

  // 4. compression (MFMA, reads C) + compressed branch (C dead after compress)
  compress_mfma<<<dim3(32, 2), 256, 0, stream>>>(C, WckT_hi, WckT_lo, WcvT_hi, WcvT_lo,
                                                 kc_hi, kc_lo, vcT);
  cscore_k<<<2048, 256, 0, stream>>>(qh, kc_hi, kc_lo, P, sel);
  outc_k<<<256, 256, 0, stream>>>(P, vcT, oc);

  // 5. selected + window + gated combine
  nsa_swl<<<8192, 256, 0, stream>>>(qhf, khfT, vhf, sel, oc, gates, outf);

  // 6. output projection (64x128 swizzled, 256 blocks — r8-verified)
  gemm_bt64<<<dim3(8, 32), 256, 0, stream>>>(outf, Wot, out, 1024, 1024, 1024);
}